// Round 4
// baseline (877.818 us; speedup 1.0000x reference)
//
#include <hip/hip_runtime.h>

typedef __attribute__((ext_vector_type(8))) short short8;
typedef __attribute__((ext_vector_type(4))) float f32x4;

#define B_SZ 8192
#define H_SZ 1024
#define R_SZ 16

__device__ __forceinline__ unsigned short f2bf(float f) {
  union { float f; unsigned u; } v; v.f = f;
  unsigned u = v.u + 0x7FFFu + ((v.u >> 16) & 1u);
  return (unsigned short)(u >> 16);
}

// ------------- transpose + convert: src[rows][cols] f32 -> dst[cols][rows] bf16 -------------
__global__ __launch_bounds__(256) void transpose_cvt(const float* __restrict__ src,
                                                     unsigned short* __restrict__ dst,
                                                     int rows, int cols) {
  __shared__ float t[32][33];
  size_t zoff = (size_t)blockIdx.z * (size_t)rows * cols;
  int c0 = blockIdx.x * 32, r0 = blockIdx.y * 32;
  int tx = threadIdx.x, ty = threadIdx.y;
#pragma unroll
  for (int i = 0; i < 4; ++i)
    t[ty + 8 * i][tx] = src[zoff + (size_t)(r0 + ty + 8 * i) * cols + c0 + tx];
  __syncthreads();
#pragma unroll
  for (int i = 0; i < 4; ++i)
    dst[zoff + (size_t)(c0 + ty + 8 * i) * rows + r0 + tx] = f2bf(t[tx][ty + 8 * i]);
}

// ------------- Wa [1024][16] f32 -> WaT [16][1024] f32 -------------
__global__ __launch_bounds__(256) void transpose_wa(const float* __restrict__ Wa,
                                                    float* __restrict__ WaT) {
  int t = blockIdx.x * 256 + threadIdx.x;  // 16384 total
  int h = t >> 4, r = t & 15;
  WaT[r * H_SZ + h] = Wa[t];
}

// ------------- gate + xb emit -------------
__global__ __launch_bounds__(256) void gate_kernel(const float* __restrict__ x,
                                                   const float* __restrict__ WaT,
                                                   const float* __restrict__ ba,
                                                   const float* __restrict__ Wc,
                                                   const float* __restrict__ bc,
                                                   float* __restrict__ comb,
                                                   float* __restrict__ conf,
                                                   unsigned short* __restrict__ xb) {
  int b = blockIdx.x * 4 + (threadIdx.x >> 6);
  int l = threadIdx.x & 63;
  const float* xr = x + (size_t)b * H_SZ;
  unsigned short* xbr = xb + (size_t)b * H_SZ;
  float xv[16];
#pragma unroll
  for (int j = 0; j < 16; ++j) xv[j] = xr[l + 64 * j];
#pragma unroll
  for (int j = 0; j < 16; ++j) xbr[l + 64 * j] = f2bf(xv[j]);
  float la[16], lcf[16];
#pragma unroll
  for (int r = 0; r < 16; ++r) {
    float sa = 0.f, sc = 0.f;
#pragma unroll
    for (int j = 0; j < 16; ++j) {
      int h = l + 64 * j;
      sa += xv[j] * WaT[r * H_SZ + h];
      sc += xv[j] * Wc[r * H_SZ + h];
    }
#pragma unroll
    for (int off = 32; off > 0; off >>= 1) {
      sa += __shfl_xor(sa, off);
      sc += __shfl_xor(sc, off);
    }
    la[r] = sa + ba[r];
    lcf[r] = sc + bc[r];
  }
  float mx = la[0];
#pragma unroll
  for (int r = 1; r < 16; ++r) mx = fmaxf(mx, la[r]);
  float se = 0.f;
#pragma unroll
  for (int r = 0; r < 16; ++r) { la[r] = expf(la[r] - mx); se += la[r]; }
  float cb[16]; float cs = 0.f;
#pragma unroll
  for (int r = 0; r < 16; ++r) {
    float cf = 1.f / (1.f + expf(-lcf[r]));
    lcf[r] = cf;
    cb[r] = (la[r] / se) * cf;
    cs += cb[r];
  }
  float inv = 1.f / (cs + 1e-8f);
  if (l < 16) {
    float cv = 0.f, qv = 0.f;
#pragma unroll
    for (int r = 0; r < 16; ++r)
      if (r == l) { cv = lcf[r]; qv = cb[r] * inv; }
    conf[b * 16 + l] = cv;
    comb[b * 16 + l] = qv;
  }
}

// async global->LDS, 16B per lane; LDS dest wave-uniform base (+ lane*16 by HW)
__device__ __forceinline__ void gload16(const unsigned short* g, const unsigned short* l) {
  __builtin_amdgcn_global_load_lds(
      (const __attribute__((address_space(1))) unsigned int*)g,
      (__attribute__((address_space(3))) unsigned int*)(unsigned short*)l, 16, 0, 0);
}

#define VMCNT0 asm volatile("s_waitcnt vmcnt(0)" ::: "memory")
#define NOP ((void)0)

// ------------- 8-phase NT bf16 GEMM: BM=256 x BN, BK=64, 8 waves (2M x 4N) -------------
// MODE 0: Hp[m,n] = bf16( relu(acc + b1[r,d]) * comb[m,r] ),  r = r_base + n/1024
// MODE 1: Out[m,n] (+)= acc (+ sum_r comb[m,r]*b2[r,n] when !accum)
template <int BN, int MODE>
__global__ __launch_bounds__(512, 1) void gemm8p(
    const unsigned short* __restrict__ A, int lda,
    const unsigned short* __restrict__ Bm, int ldb, int K,
    unsigned short* __restrict__ Hp, int ldh,
    const float* __restrict__ b1v,
    float* __restrict__ Out,
    const float* __restrict__ b2v,
    const float* __restrict__ comb,
    int r_base, int accum) {
  constexpr int ASZ = 256 * 64;       // elems per A tile
  constexpr int BSZ = BN * 64;        // elems per B tile
  constexpr int NQ = BN / 128;        // B frags per quadrant (2 or 1)
  constexpr int BLOADS = BN / 64;     // B gload rounds per tile (4 or 2)
  __shared__ unsigned short smem[2 * (ASZ + BSZ)];  // 128 KB (BN=256) / 96 KB (BN=128)

  const int tid = threadIdx.x;
  const int lane = tid & 63;
  const int wid = tid >> 6;
  const int wm = wid >> 2;            // 0..1
  const int wn = wid & 3;             // 0..3
  const int lr = lane >> 4, lc = lane & 15;
  const int bn0 = blockIdx.x * BN;
  const int bm0 = blockIdx.y * 256;
  const int KT = K >> 6;

  f32x4 acc[8][2 * NQ];
#pragma unroll
  for (int i = 0; i < 8; ++i)
#pragma unroll
    for (int j = 0; j < 2 * NQ; ++j) acc[i][j] = {0.f, 0.f, 0.f, 0.f};

  // stage full A tile (256x64, 4 rounds) / B tile (BNx64) of K-tile kt into buffer bf.
  // LDS linear dest; source chunk pre-swizzled (involution c^=row&7) so swizzled reads work.
  auto stageA = [&](int bf, int kt) {
    const unsigned short* base = smem + (bf ? (ASZ + BSZ) : 0);
#pragma unroll
    for (int q = 0; q < 4; ++q) {
      int rl = (q * 512 + tid) >> 3;           // 0..255
      int ck = (tid & 7) ^ (rl & 7);
      gload16(A + (size_t)(bm0 + rl) * lda + kt * 64 + ck * 8,
              base + q * 4096 + (tid & ~63) * 8);
    }
  };
  auto stageB = [&](int bf, int kt) {
    const unsigned short* base = smem + (bf ? (ASZ + BSZ) : 0) + ASZ;
#pragma unroll
    for (int q = 0; q < BLOADS; ++q) {
      int rl = (q * 512 + tid) >> 3;           // 0..BN-1
      int ck = (tid & 7) ^ (rl & 7);
      gload16(Bm + (size_t)(bn0 + rl) * ldb + kt * 64 + ck * 8,
              base + q * 4096 + (tid & ~63) * 8);
    }
  };

// one phase: ds_read quadrant (MH,NH) frags; issue staging; barrier; MFMA x16; tail; barrier
#define PHASE(BF, MH, NH, STG, TAIL)                                               \
  {                                                                                \
    const unsigned short* As = smem + (BF ? (ASZ + BSZ) : 0);                      \
    const unsigned short* Bs = As + ASZ;                                           \
    short8 af[2][4];                                                               \
    short8 bg[2][NQ];                                                              \
    _Pragma("unroll") for (int c = 0; c < 2; ++c) {                                \
      _Pragma("unroll") for (int f = 0; f < 4; ++f) {                              \
        int ra = wm * 128 + MH * 64 + f * 16 + lc;                                 \
        af[c][f] = *(const short8*)(As + ra * 64 + (((c * 4 + lr) ^ (ra & 7)) * 8)); \
      }                                                                            \
      _Pragma("unroll") for (int g = 0; g < NQ; ++g) {                             \
        int rb = wn * (BN / 4) + NH * (BN / 8) + g * 16 + lc;                      \
        bg[c][g] = *(const short8*)(Bs + rb * 64 + (((c * 4 + lr) ^ (rb & 7)) * 8)); \
      }                                                                            \
    }                                                                              \
    STG;                                                                           \
    __builtin_amdgcn_s_barrier();                                                  \
    __builtin_amdgcn_s_setprio(1);                                                 \
    _Pragma("unroll") for (int c = 0; c < 2; ++c)                                  \
      _Pragma("unroll") for (int f = 0; f < 4; ++f)                                \
        _Pragma("unroll") for (int g = 0; g < NQ; ++g)                             \
          acc[MH * 4 + f][NH * NQ + g] = __builtin_amdgcn_mfma_f32_16x16x32_bf16(  \
              af[c][f], bg[c][g], acc[MH * 4 + f][NH * NQ + g], 0, 0, 0);          \
    __builtin_amdgcn_s_setprio(0);                                                 \
    TAIL;                                                                          \
    __builtin_amdgcn_s_barrier();                                                  \
  }

  // prologue: tile 0 -> buf0, drain, sync
  stageA(0, 0);
  stageB(0, 0);
  VMCNT0;
  __builtin_amdgcn_s_barrier();

  const int P = KT >> 1;  // K multiple of 128 guaranteed (K = G*1024 or 1024)
  for (int i = 0; i < P; ++i) {
    const int t1 = 2 * i + 1, t2 = 2 * i + 2;
    // tile 2i from buf0; stage tile 2i+1 -> buf1 during p1/p2; drain it at p4
    PHASE(0, 0, 0, stageA(1, t1), NOP)
    PHASE(0, 0, 1, stageB(1, t1), NOP)
    PHASE(0, 1, 0, NOP, NOP)
    PHASE(0, 1, 1, NOP, VMCNT0)
    // tile 2i+1 from buf1; stage tile 2i+2 -> buf0 during p5/p6; drain at p8
    PHASE(1, 0, 0, if (t2 < KT) stageA(0, t2), NOP)
    PHASE(1, 0, 1, if (t2 < KT) stageB(0, t2), NOP)
    PHASE(1, 1, 0, NOP, NOP)
    PHASE(1, 1, 1, NOP, VMCNT0)
  }
#undef PHASE

  // epilogue: C/D layout col=lane&15, row=(lane>>4)*4+reg; col offset = j*16 (both NQ)
#pragma unroll
  for (int ii = 0; ii < 8; ++ii) {
#pragma unroll
    for (int jj = 0; jj < 2 * NQ; ++jj) {
      int m0 = bm0 + wm * 128 + ii * 16 + lr * 4;
      int n = bn0 + wn * (BN / 4) + jj * 16 + lc;
      f32x4 a = acc[ii][jj];
      if (MODE == 0) {
        int r = r_base + (n >> 10);
        int d = n & 1023;
        float bias = b1v[r * H_SZ + d];
#pragma unroll
        for (int j = 0; j < 4; ++j) {
          float v = fmaxf(a[j] + bias, 0.f) * comb[(size_t)(m0 + j) * 16 + r];
          Hp[(size_t)(m0 + j) * ldh + n] = f2bf(v);
        }
      } else {
#pragma unroll
        for (int j = 0; j < 4; ++j) {
          size_t row = (size_t)(m0 + j);
          float v = a[j];
          if (accum) {
            v += Out[row * H_SZ + n];
          } else {
            float bs = 0.f;
#pragma unroll
            for (int r = 0; r < 16; ++r)
              bs += comb[row * 16 + r] * b2v[r * H_SZ + n];
            v += bs;
          }
          Out[row * H_SZ + n] = v;
        }
      }
    }
  }
}

extern "C" void kernel_launch(void* const* d_in, const int* in_sizes, int n_in,
                              void* d_out, int out_size, void* d_ws, size_t ws_size,
                              hipStream_t stream) {
  if (n_in < 9) return;
  const float* x  = (const float*)d_in[0];
  const float* Wa = (const float*)d_in[1];
  const float* ba = (const float*)d_in[2];
  const float* W1 = (const float*)d_in[3];
  const float* b1 = (const float*)d_in[4];
  const float* W2 = (const float*)d_in[5];
  const float* b2 = (const float*)d_in[6];
  const float* Wc = (const float*)d_in[7];
  const float* bc = (const float*)d_in[8];

  float* out = (float*)d_out;
  float* conf = out + (size_t)B_SZ * H_SZ;

  char* w = (char*)d_ws;
  unsigned short* xb = (unsigned short*)w;  w += (size_t)B_SZ * H_SZ * 2;
  unsigned short* W1T = (unsigned short*)w; w += (size_t)R_SZ * H_SZ * H_SZ * 2;
  unsigned short* W2T = (unsigned short*)w; w += (size_t)R_SZ * H_SZ * H_SZ * 2;
  float* comb = (float*)w;                  w += (size_t)B_SZ * R_SZ * 4;
  float* WaT = (float*)w;                   w += (size_t)R_SZ * H_SZ * 4;
  unsigned short* Hp = (unsigned short*)w;
  size_t used = (size_t)(w - (char*)d_ws);

  // pick largest rule-group size G whose Hp buffer fits in remaining ws
  int G = 16;
  while (G > 1 && used + (size_t)B_SZ * G * H_SZ * 2 > ws_size) G >>= 1;
  if (used + (size_t)B_SZ * G * H_SZ * 2 > ws_size) return;  // ws too small

  dim3 tb(32, 8);
  transpose_cvt<<<dim3(32, 32, 16), tb, 0, stream>>>(W1, W1T, H_SZ, H_SZ);
  transpose_cvt<<<dim3(32, 512, 1), tb, 0, stream>>>(W2, W2T, R_SZ * H_SZ, H_SZ);
  transpose_wa<<<dim3(64), dim3(256), 0, stream>>>(Wa, WaT);
  gate_kernel<<<dim3(B_SZ / 4), dim3(256), 0, stream>>>(x, WaT, ba, Wc, bc, comb, conf, xb);

  int ngroups = R_SZ / G;
  for (int g = 0; g < ngroups; ++g) {
    // Hp[b, (r_local,d)] = comb[b,r] * relu(x @ W1[r] + b1[r])   for r in group g
    gemm8p<256, 0><<<dim3(G * 4, B_SZ / 256), dim3(512), 0, stream>>>(
        xb, H_SZ,
        W1T + (size_t)g * G * H_SZ * H_SZ, H_SZ, H_SZ,
        Hp, G * H_SZ, b1, nullptr, nullptr, comb, g * G, 0);
    // out[b,o] (+)= Hp @ W2[group rows]  (+ gate-weighted b2 on first group)
    gemm8p<128, 1><<<dim3(H_SZ / 128, B_SZ / 256), dim3(512), 0, stream>>>(
        Hp, G * H_SZ,
        W2T + (size_t)g * G * H_SZ, R_SZ * H_SZ, G * H_SZ,
        nullptr, 0, nullptr, out, b2, comb, 0, (g > 0) ? 1 : 0);
  }
}

// Round 5
// 792.905 us; speedup vs baseline: 1.1071x; 1.1071x over previous
//
#include <hip/hip_runtime.h>

typedef __attribute__((ext_vector_type(8))) short short8;
typedef __attribute__((ext_vector_type(4))) float f32x4;

#define B_SZ 8192
#define H_SZ 1024
#define R_SZ 16

__device__ __forceinline__ unsigned short f2bf(float f) {
  union { float f; unsigned u; } v; v.f = f;
  unsigned u = v.u + 0x7FFFu + ((v.u >> 16) & 1u);
  return (unsigned short)(u >> 16);
}

// ------------- transpose + convert: src[rows][cols] f32 -> dst[cols][rows] bf16 -------------
__global__ __launch_bounds__(256) void transpose_cvt(const float* __restrict__ src,
                                                     unsigned short* __restrict__ dst,
                                                     int rows, int cols) {
  __shared__ float t[32][33];
  size_t zoff = (size_t)blockIdx.z * (size_t)rows * cols;
  int c0 = blockIdx.x * 32, r0 = blockIdx.y * 32;
  int tx = threadIdx.x, ty = threadIdx.y;
#pragma unroll
  for (int i = 0; i < 4; ++i)
    t[ty + 8 * i][tx] = src[zoff + (size_t)(r0 + ty + 8 * i) * cols + c0 + tx];
  __syncthreads();
#pragma unroll
  for (int i = 0; i < 4; ++i)
    dst[zoff + (size_t)(c0 + ty + 8 * i) * rows + r0 + tx] = f2bf(t[tx][ty + 8 * i]);
}

// ------------- Wa [1024][16] f32 -> WaT [16][1024] f32 -------------
__global__ __launch_bounds__(256) void transpose_wa(const float* __restrict__ Wa,
                                                    float* __restrict__ WaT) {
  int t = blockIdx.x * 256 + threadIdx.x;  // 16384 total
  int h = t >> 4, r = t & 15;
  WaT[r * H_SZ + h] = Wa[t];
}

// ------------- gate + xb emit -------------
__global__ __launch_bounds__(256) void gate_kernel(const float* __restrict__ x,
                                                   const float* __restrict__ WaT,
                                                   const float* __restrict__ ba,
                                                   const float* __restrict__ Wc,
                                                   const float* __restrict__ bc,
                                                   float* __restrict__ comb,
                                                   float* __restrict__ conf,
                                                   unsigned short* __restrict__ xb) {
  int b = blockIdx.x * 4 + (threadIdx.x >> 6);
  int l = threadIdx.x & 63;
  const float* xr = x + (size_t)b * H_SZ;
  unsigned short* xbr = xb + (size_t)b * H_SZ;
  float xv[16];
#pragma unroll
  for (int j = 0; j < 16; ++j) xv[j] = xr[l + 64 * j];
#pragma unroll
  for (int j = 0; j < 16; ++j) xbr[l + 64 * j] = f2bf(xv[j]);
  float la[16], lcf[16];
#pragma unroll
  for (int r = 0; r < 16; ++r) {
    float sa = 0.f, sc = 0.f;
#pragma unroll
    for (int j = 0; j < 16; ++j) {
      int h = l + 64 * j;
      sa += xv[j] * WaT[r * H_SZ + h];
      sc += xv[j] * Wc[r * H_SZ + h];
    }
#pragma unroll
    for (int off = 32; off > 0; off >>= 1) {
      sa += __shfl_xor(sa, off);
      sc += __shfl_xor(sc, off);
    }
    la[r] = sa + ba[r];
    lcf[r] = sc + bc[r];
  }
  float mx = la[0];
#pragma unroll
  for (int r = 1; r < 16; ++r) mx = fmaxf(mx, la[r]);
  float se = 0.f;
#pragma unroll
  for (int r = 0; r < 16; ++r) { la[r] = expf(la[r] - mx); se += la[r]; }
  float cb[16]; float cs = 0.f;
#pragma unroll
  for (int r = 0; r < 16; ++r) {
    float cf = 1.f / (1.f + expf(-lcf[r]));
    lcf[r] = cf;
    cb[r] = (la[r] / se) * cf;
    cs += cb[r];
  }
  float inv = 1.f / (cs + 1e-8f);
  if (l < 16) {
    float cv = 0.f, qv = 0.f;
#pragma unroll
    for (int r = 0; r < 16; ++r)
      if (r == l) { cv = lcf[r]; qv = cb[r] * inv; }
    conf[b * 16 + l] = cv;
    comb[b * 16 + l] = qv;
  }
}

// async global->LDS, 16B per lane; LDS dest wave-uniform base (+ lane*16 by HW)
__device__ __forceinline__ void gload16(const unsigned short* g, const unsigned short* l) {
  __builtin_amdgcn_global_load_lds(
      (const __attribute__((address_space(1))) unsigned int*)g,
      (__attribute__((address_space(3))) unsigned int*)(unsigned short*)l, 16, 0, 0);
}

// ------------- 3-buffer counted-vmcnt NT bf16 GEMM -------------
// BM=256, BN=128, BK=64; 8 waves as 4M x 2N (64x64 wave tile -> Fa=Fb=4 per phase).
// 3 LDS buffers (144KB), stage tile t+2 at phase A of tile t, tail vmcnt(6) at
// phase B (= exactly the 6 loads of the newest stage) -> prefetch depth 2 tiles,
// no vmcnt(0) in the main loop.
// MODE 0: Hp[m,n] = bf16( relu(acc + b1[r,d]) * comb[m,r] ),  r = r_base + n/1024
// MODE 1: Out[m,n] (+)= acc (+ sum_r comb[m,r]*b2[r,n] when !accum)
template <int MODE>
__global__ __launch_bounds__(512, 1) void gemm3b(
    const unsigned short* __restrict__ A, int lda,
    const unsigned short* __restrict__ Bm, int ldb, int K,
    unsigned short* __restrict__ Hp, int ldh,
    const float* __restrict__ b1v,
    float* __restrict__ Out,
    const float* __restrict__ b2v,
    const float* __restrict__ comb,
    int r_base, int accum) {
  constexpr int ABUF = 256 * 64;        // 16384 elems (32KB)
  constexpr int BBUF = 128 * 64;        // 8192 elems  (16KB)
  constexpr int BUFE = ABUF + BBUF;     // 24576 elems (48KB)
  __shared__ unsigned short smem[3 * BUFE];  // 144KB

  const int tid = threadIdx.x;
  const int lane = tid & 63;
  const int wid = tid >> 6;
  const int wm = wid >> 1;              // 0..3  (64-row strip)
  const int wn = wid & 1;               // 0..1  (64-col strip)
  const int lr = lane >> 4, lc = lane & 15;
  const int bn0 = blockIdx.x * 128;
  const int bm0 = blockIdx.y * 256;
  const int KT = K >> 6;                // >= 16, even

  f32x4 acc[4][4];
#pragma unroll
  for (int i = 0; i < 4; ++i)
#pragma unroll
    for (int j = 0; j < 4; ++j) acc[i][j] = {0.f, 0.f, 0.f, 0.f};

  // 6 global_load_lds per wave per tile (A:4, B:2); linear LDS dest,
  // source chunk pre-swizzled with the involution c ^= row&7.
  auto stage = [&](int buf, int kt) {
    const unsigned short* base = smem + buf * BUFE;
#pragma unroll
    for (int q = 0; q < 4; ++q) {
      int rl = (q * 512 + tid) >> 3;
      int ck = (tid & 7) ^ (rl & 7);
      gload16(A + (size_t)(bm0 + rl) * lda + kt * 64 + ck * 8,
              base + q * 4096 + (tid & ~63) * 8);
    }
#pragma unroll
    for (int q = 0; q < 2; ++q) {
      int rl = (q * 512 + tid) >> 3;
      int ck = (tid & 7) ^ (rl & 7);
      gload16(Bm + (size_t)(bn0 + rl) * ldb + kt * 64 + ck * 8,
              base + ABUF + q * 4096 + (tid & ~63) * 8);
    }
  };

  // prologue: tiles 0,1 in flight; force S(0) resident (6 newest = S(1) may fly)
  stage(0, 0);
  stage(1, 1);
  asm volatile("s_waitcnt vmcnt(6)" ::: "memory");
  __builtin_amdgcn_s_barrier();

  for (int t = 0; t < KT; ++t) {
    const unsigned short* As = smem + (t % 3) * BUFE;
    const unsigned short* Bs = As + ABUF;
    short8 af[4], bg[4];
    // ---- phase A (k-half c=0): ds_read + issue stage(t+2) ----
#pragma unroll
    for (int f = 0; f < 4; ++f) {
      int ra = wm * 64 + f * 16 + lc;
      af[f] = *(const short8*)(As + ra * 64 + ((lr ^ (ra & 7)) * 8));
      int rb = wn * 64 + f * 16 + lc;
      bg[f] = *(const short8*)(Bs + rb * 64 + ((lr ^ (rb & 7)) * 8));
    }
    if (t + 2 < KT) stage((t + 2) % 3, t + 2);
    __builtin_amdgcn_s_barrier();
    __builtin_amdgcn_s_setprio(1);
#pragma unroll
    for (int f = 0; f < 4; ++f)
#pragma unroll
      for (int g = 0; g < 4; ++g)
        acc[f][g] = __builtin_amdgcn_mfma_f32_16x16x32_bf16(af[f], bg[g], acc[f][g], 0, 0, 0);
    __builtin_amdgcn_s_setprio(0);
    __builtin_amdgcn_s_barrier();
    // ---- phase B (k-half c=1): ds_read + MFMA + counted tail wait ----
#pragma unroll
    for (int f = 0; f < 4; ++f) {
      int ra = wm * 64 + f * 16 + lc;
      af[f] = *(const short8*)(As + ra * 64 + (((4 + lr) ^ (ra & 7)) * 8));
      int rb = wn * 64 + f * 16 + lc;
      bg[f] = *(const short8*)(Bs + rb * 64 + (((4 + lr) ^ (rb & 7)) * 8));
    }
    __builtin_amdgcn_s_barrier();
    __builtin_amdgcn_s_setprio(1);
#pragma unroll
    for (int f = 0; f < 4; ++f)
#pragma unroll
      for (int g = 0; g < 4; ++g)
        acc[f][g] = __builtin_amdgcn_mfma_f32_16x16x32_bf16(af[f], bg[g], acc[f][g], 0, 0, 0);
    __builtin_amdgcn_s_setprio(0);
    if (t + 2 < KT) {
      // S(t+1) must be resident next iter; newest 6 outstanding = S(t+2)
      asm volatile("s_waitcnt vmcnt(6)" ::: "memory");
    } else if (t + 1 < KT) {
      asm volatile("s_waitcnt vmcnt(0)" ::: "memory");  // last prefetched tile
    }
    __builtin_amdgcn_s_barrier();
  }

  // epilogue: C/D layout col=lane&15, row=(lane>>4)*4+reg
#pragma unroll
  for (int f = 0; f < 4; ++f) {
#pragma unroll
    for (int g = 0; g < 4; ++g) {
      int m0 = bm0 + wm * 64 + f * 16 + lr * 4;
      int n = bn0 + wn * 64 + g * 16 + lc;
      f32x4 a = acc[f][g];
      if (MODE == 0) {
        int r = r_base + (n >> 10);
        int d = n & 1023;
        float bias = b1v[r * H_SZ + d];
#pragma unroll
        for (int j = 0; j < 4; ++j) {
          float v = fmaxf(a[j] + bias, 0.f) * comb[(size_t)(m0 + j) * 16 + r];
          Hp[(size_t)(m0 + j) * ldh + n] = f2bf(v);
        }
      } else {
#pragma unroll
        for (int j = 0; j < 4; ++j) {
          size_t row = (size_t)(m0 + j);
          float v = a[j];
          if (accum) {
            v += Out[row * H_SZ + n];
          } else {
            float bs = 0.f;
#pragma unroll
            for (int r = 0; r < 16; ++r)
              bs += comb[row * 16 + r] * b2v[r * H_SZ + n];
            v += bs;
          }
          Out[row * H_SZ + n] = v;
        }
      }
    }
  }
}

extern "C" void kernel_launch(void* const* d_in, const int* in_sizes, int n_in,
                              void* d_out, int out_size, void* d_ws, size_t ws_size,
                              hipStream_t stream) {
  if (n_in < 9) return;
  const float* x  = (const float*)d_in[0];
  const float* Wa = (const float*)d_in[1];
  const float* ba = (const float*)d_in[2];
  const float* W1 = (const float*)d_in[3];
  const float* b1 = (const float*)d_in[4];
  const float* W2 = (const float*)d_in[5];
  const float* b2 = (const float*)d_in[6];
  const float* Wc = (const float*)d_in[7];
  const float* bc = (const float*)d_in[8];

  float* out = (float*)d_out;
  float* conf = out + (size_t)B_SZ * H_SZ;

  char* w = (char*)d_ws;
  unsigned short* xb = (unsigned short*)w;  w += (size_t)B_SZ * H_SZ * 2;
  unsigned short* W1T = (unsigned short*)w; w += (size_t)R_SZ * H_SZ * H_SZ * 2;
  unsigned short* W2T = (unsigned short*)w; w += (size_t)R_SZ * H_SZ * H_SZ * 2;
  float* comb = (float*)w;                  w += (size_t)B_SZ * R_SZ * 4;
  float* WaT = (float*)w;                   w += (size_t)R_SZ * H_SZ * 4;
  unsigned short* Hp = (unsigned short*)w;
  size_t used = (size_t)(w - (char*)d_ws);

  // pick largest rule-group size G whose Hp buffer fits in remaining ws
  int G = 16;
  while (G > 1 && used + (size_t)B_SZ * G * H_SZ * 2 > ws_size) G >>= 1;
  if (used + (size_t)B_SZ * G * H_SZ * 2 > ws_size) return;  // ws too small

  dim3 tb(32, 8);
  transpose_cvt<<<dim3(32, 32, 16), tb, 0, stream>>>(W1, W1T, H_SZ, H_SZ);
  transpose_cvt<<<dim3(32, 512, 1), tb, 0, stream>>>(W2, W2T, R_SZ * H_SZ, H_SZ);
  transpose_wa<<<dim3(64), dim3(256), 0, stream>>>(Wa, WaT);
  gate_kernel<<<dim3(B_SZ / 4), dim3(256), 0, stream>>>(x, WaT, ba, Wc, bc, comb, conf, xb);

  int ngroups = R_SZ / G;
  for (int g = 0; g < ngroups; ++g) {
    // Hp[b, (r_local,d)] = comb[b,r] * relu(x @ W1[r] + b1[r])   for r in group g
    gemm3b<0><<<dim3(G * 8, B_SZ / 256), dim3(512), 0, stream>>>(
        xb, H_SZ,
        W1T + (size_t)g * G * H_SZ * H_SZ, H_SZ, H_SZ,
        Hp, G * H_SZ, b1, nullptr, nullptr, comb, g * G, 0);
    // out[b,o] (+)= Hp @ W2[group rows]  (+ gate-weighted b2 on first group)
    gemm3b<1><<<dim3(H_SZ / 128, B_SZ / 256), dim3(512), 0, stream>>>(
        Hp, G * H_SZ,
        W2T + (size_t)g * G * H_SZ, R_SZ * H_SZ, G * H_SZ,
        nullptr, 0, nullptr, out, b2, comb, 0, (g > 0) ? 1 : 0);
  }
}

// Round 6
// 769.813 us; speedup vs baseline: 1.1403x; 1.0300x over previous
//
#include <hip/hip_runtime.h>

typedef __attribute__((ext_vector_type(8))) short short8;
typedef __attribute__((ext_vector_type(4))) float f32x4;

#define B_SZ 8192
#define H_SZ 1024
#define R_SZ 16

__device__ __forceinline__ unsigned short f2bf(float f) {
  union { float f; unsigned u; } v; v.f = f;
  unsigned u = v.u + 0x7FFFu + ((v.u >> 16) & 1u);
  return (unsigned short)(u >> 16);
}

// ------------- transpose + convert: src[rows][cols] f32 -> dst[cols][rows] bf16 -------------
__global__ __launch_bounds__(256) void transpose_cvt(const float* __restrict__ src,
                                                     unsigned short* __restrict__ dst,
                                                     int rows, int cols) {
  __shared__ float t[32][33];
  size_t zoff = (size_t)blockIdx.z * (size_t)rows * cols;
  int c0 = blockIdx.x * 32, r0 = blockIdx.y * 32;
  int tx = threadIdx.x, ty = threadIdx.y;
#pragma unroll
  for (int i = 0; i < 4; ++i)
    t[ty + 8 * i][tx] = src[zoff + (size_t)(r0 + ty + 8 * i) * cols + c0 + tx];
  __syncthreads();
#pragma unroll
  for (int i = 0; i < 4; ++i)
    dst[zoff + (size_t)(c0 + ty + 8 * i) * rows + r0 + tx] = f2bf(t[tx][ty + 8 * i]);
}

// ------------- Wa [1024][16] f32 -> WaT [16][1024] f32 -------------
__global__ __launch_bounds__(256) void transpose_wa(const float* __restrict__ Wa,
                                                    float* __restrict__ WaT) {
  int t = blockIdx.x * 256 + threadIdx.x;  // 16384 total
  int h = t >> 4, r = t & 15;
  WaT[r * H_SZ + h] = Wa[t];
}

// ------------- gate + xb emit -------------
__global__ __launch_bounds__(256) void gate_kernel(const float* __restrict__ x,
                                                   const float* __restrict__ WaT,
                                                   const float* __restrict__ ba,
                                                   const float* __restrict__ Wc,
                                                   const float* __restrict__ bc,
                                                   float* __restrict__ comb,
                                                   float* __restrict__ conf,
                                                   unsigned short* __restrict__ xb) {
  int b = blockIdx.x * 4 + (threadIdx.x >> 6);
  int l = threadIdx.x & 63;
  const float* xr = x + (size_t)b * H_SZ;
  unsigned short* xbr = xb + (size_t)b * H_SZ;
  float xv[16];
#pragma unroll
  for (int j = 0; j < 16; ++j) xv[j] = xr[l + 64 * j];
#pragma unroll
  for (int j = 0; j < 16; ++j) xbr[l + 64 * j] = f2bf(xv[j]);
  float la[16], lcf[16];
#pragma unroll
  for (int r = 0; r < 16; ++r) {
    float sa = 0.f, sc = 0.f;
#pragma unroll
    for (int j = 0; j < 16; ++j) {
      int h = l + 64 * j;
      sa += xv[j] * WaT[r * H_SZ + h];
      sc += xv[j] * Wc[r * H_SZ + h];
    }
#pragma unroll
    for (int off = 32; off > 0; off >>= 1) {
      sa += __shfl_xor(sa, off);
      sc += __shfl_xor(sc, off);
    }
    la[r] = sa + ba[r];
    lcf[r] = sc + bc[r];
  }
  float mx = la[0];
#pragma unroll
  for (int r = 1; r < 16; ++r) mx = fmaxf(mx, la[r]);
  float se = 0.f;
#pragma unroll
  for (int r = 0; r < 16; ++r) { la[r] = expf(la[r] - mx); se += la[r]; }
  float cb[16]; float cs = 0.f;
#pragma unroll
  for (int r = 0; r < 16; ++r) {
    float cf = 1.f / (1.f + expf(-lcf[r]));
    lcf[r] = cf;
    cb[r] = (la[r] / se) * cf;
    cs += cb[r];
  }
  float inv = 1.f / (cs + 1e-8f);
  if (l < 16) {
    float cv = 0.f, qv = 0.f;
#pragma unroll
    for (int r = 0; r < 16; ++r)
      if (r == l) { cv = lcf[r]; qv = cb[r] * inv; }
    conf[b * 16 + l] = cv;
    comb[b * 16 + l] = qv;
  }
}

// ------------- NT bf16 GEMM, 128x128 tile, BK=64, 4 waves, 32KB LDS, reg prefetch -------------
// R3 structure + burst discipline: {all 16 ds_reads} -> lgkmcnt(0)+sched_barrier ->
// {32-MFMA dependency-free burst}. Matrix pipe runs at burst rate instead of
// trickling at the 8-wave-shared LDS return rate.
// MODE 0: Hp[m,n] = bf16( relu(acc + b1[r,d]) * comb[m,r] ),  r = r_base + n/1024
// MODE 1: Out[m,n] (+)= acc (+ sum_r comb[m,r]*b2[r,n] when !accum)
template <int MODE>
__global__ __launch_bounds__(256) void gemm_nt(
    const unsigned short* __restrict__ A, int lda,
    const unsigned short* __restrict__ B, int ldb, int K,
    unsigned short* __restrict__ Hp, int ldh,
    const float* __restrict__ b1v,
    float* __restrict__ Out,
    const float* __restrict__ b2v,
    const float* __restrict__ comb,
    int r_base, int accum) {
  __shared__ short smem[16384];  // A tile [128][64] bf16 (16KB) + B tile (16KB)
  short* As = smem;
  short* Bs = smem + 8192;

  const int tid = threadIdx.x;
  const int lane = tid & 63;
  const int wid = tid >> 6;
  const int wm = wid >> 1, wn = wid & 1;
  const int lr = lane >> 4, lc = lane & 15;

  const int bn0 = blockIdx.x * 128;
  const int bm0 = blockIdx.y * 128;

  int srow[4], ssc[4];
#pragma unroll
  for (int i = 0; i < 4; ++i) {
    int idx = i * 256 + tid;
    srow[i] = idx >> 3;   // tile row 0..127
    ssc[i] = idx & 7;     // 16B chunk within 128B row
  }

  const f32x4 zero = {0.f, 0.f, 0.f, 0.f};
  f32x4 acc[4][4];
#pragma unroll
  for (int i = 0; i < 4; ++i)
#pragma unroll
    for (int j = 0; j < 4; ++j) acc[i][j] = zero;

  const int KT = K >> 6;

  short8 va[4], vb[4];
#pragma unroll
  for (int i = 0; i < 4; ++i) {
    va[i] = *(const short8*)(A + (size_t)(bm0 + srow[i]) * lda + ssc[i] * 8);
    vb[i] = *(const short8*)(B + (size_t)(bn0 + srow[i]) * ldb + ssc[i] * 8);
  }

  for (int kt = 0; kt < KT; ++kt) {
    __syncthreads();  // previous tile's reads complete
#pragma unroll
    for (int i = 0; i < 4; ++i) {
      // XOR-swizzle: logical chunk c stored at slot c^(row&7)  (bank-conflict-free reads)
      *(short8*)(As + srow[i] * 64 + ((ssc[i] ^ (srow[i] & 7)) * 8)) = va[i];
      *(short8*)(Bs + srow[i] * 64 + ((ssc[i] ^ (srow[i] & 7)) * 8)) = vb[i];
    }
    __syncthreads();
    if (kt + 1 < KT) {  // prefetch next tile into regs; vmem flies under the bursts
      int k0 = (kt + 1) << 6;
#pragma unroll
      for (int i = 0; i < 4; ++i) {
        va[i] = *(const short8*)(A + (size_t)(bm0 + srow[i]) * lda + k0 + ssc[i] * 8);
        vb[i] = *(const short8*)(B + (size_t)(bn0 + srow[i]) * ldb + k0 + ssc[i] * 8);
      }
    }
    // ---- read burst: all 16 ds_read_b128 for this K-tile ----
    short8 af[2][4], bfr[2][4];
#pragma unroll
    for (int c = 0; c < 2; ++c) {
#pragma unroll
      for (int f = 0; f < 4; ++f) {
        int ra = wm * 64 + f * 16 + lc;
        af[c][f] = *(const short8*)(As + ra * 64 + (((c * 4 + lr) ^ (ra & 7)) * 8));
        int rb = wn * 64 + f * 16 + lc;
        bfr[c][f] = *(const short8*)(Bs + rb * 64 + (((c * 4 + lr) ^ (rb & 7)) * 8));
      }
    }
    // drain LDS returns once, then fence scheduling so the MFMA burst stays below
    asm volatile("s_waitcnt lgkmcnt(0)" ::: "memory");
    __builtin_amdgcn_sched_barrier(0);
    // ---- MFMA burst: 32 dependency-free MFMAs ----
#pragma unroll
    for (int c = 0; c < 2; ++c)
#pragma unroll
      for (int mf = 0; mf < 4; ++mf)
#pragma unroll
        for (int nf = 0; nf < 4; ++nf)
          acc[mf][nf] = __builtin_amdgcn_mfma_f32_16x16x32_bf16(af[c][mf], bfr[c][nf],
                                                                acc[mf][nf], 0, 0, 0);
  }

  // epilogue: C/D layout col=lane&15, row=(lane>>4)*4+reg
#pragma unroll
  for (int mf = 0; mf < 4; ++mf) {
#pragma unroll
    for (int nf = 0; nf < 4; ++nf) {
      int m0 = bm0 + wm * 64 + mf * 16 + lr * 4;
      int n = bn0 + wn * 64 + nf * 16 + lc;
      f32x4 a = acc[mf][nf];
      if (MODE == 0) {
        int r = r_base + (n >> 10);
        int d = n & 1023;
        float bias = b1v[r * H_SZ + d];
#pragma unroll
        for (int j = 0; j < 4; ++j) {
          float v = fmaxf(a[j] + bias, 0.f) * comb[(size_t)(m0 + j) * 16 + r];
          Hp[(size_t)(m0 + j) * ldh + n] = f2bf(v);
        }
      } else {
#pragma unroll
        for (int j = 0; j < 4; ++j) {
          size_t row = (size_t)(m0 + j);
          float v = a[j];
          if (accum) {
            v += Out[row * H_SZ + n];
          } else {
            float bs = 0.f;
#pragma unroll
            for (int r = 0; r < 16; ++r)
              bs += comb[row * 16 + r] * b2v[r * H_SZ + n];
            v += bs;
          }
          Out[row * H_SZ + n] = v;
        }
      }
    }
  }
}

extern "C" void kernel_launch(void* const* d_in, const int* in_sizes, int n_in,
                              void* d_out, int out_size, void* d_ws, size_t ws_size,
                              hipStream_t stream) {
  if (n_in < 9) return;
  const float* x  = (const float*)d_in[0];
  const float* Wa = (const float*)d_in[1];
  const float* ba = (const float*)d_in[2];
  const float* W1 = (const float*)d_in[3];
  const float* b1 = (const float*)d_in[4];
  const float* W2 = (const float*)d_in[5];
  const float* b2 = (const float*)d_in[6];
  const float* Wc = (const float*)d_in[7];
  const float* bc = (const float*)d_in[8];

  float* out = (float*)d_out;
  float* conf = out + (size_t)B_SZ * H_SZ;

  char* w = (char*)d_ws;
  unsigned short* xb = (unsigned short*)w;  w += (size_t)B_SZ * H_SZ * 2;
  unsigned short* W1T = (unsigned short*)w; w += (size_t)R_SZ * H_SZ * H_SZ * 2;
  unsigned short* W2T = (unsigned short*)w; w += (size_t)R_SZ * H_SZ * H_SZ * 2;
  float* comb = (float*)w;                  w += (size_t)B_SZ * R_SZ * 4;
  float* WaT = (float*)w;                   w += (size_t)R_SZ * H_SZ * 4;
  unsigned short* Hp = (unsigned short*)w;
  size_t used = (size_t)(w - (char*)d_ws);

  // pick largest rule-group size G whose Hp buffer fits in remaining ws
  int G = 16;
  while (G > 1 && used + (size_t)B_SZ * G * H_SZ * 2 > ws_size) G >>= 1;
  if (used + (size_t)B_SZ * G * H_SZ * 2 > ws_size) return;  // ws too small

  dim3 tb(32, 8);
  transpose_cvt<<<dim3(32, 32, 16), tb, 0, stream>>>(W1, W1T, H_SZ, H_SZ);
  transpose_cvt<<<dim3(32, 512, 1), tb, 0, stream>>>(W2, W2T, R_SZ * H_SZ, H_SZ);
  transpose_wa<<<dim3(64), dim3(256), 0, stream>>>(Wa, WaT);
  gate_kernel<<<dim3(B_SZ / 4), dim3(256), 0, stream>>>(x, WaT, ba, Wc, bc, comb, conf, xb);

  int ngroups = R_SZ / G;
  for (int g = 0; g < ngroups; ++g) {
    // Hp[b, (r_local,d)] = comb[b,r] * relu(x @ W1[r] + b1[r])   for r in group g
    gemm_nt<0><<<dim3(G * 8, 64), dim3(256), 0, stream>>>(
        xb, H_SZ,
        W1T + (size_t)g * G * H_SZ * H_SZ, H_SZ, H_SZ,
        Hp, G * H_SZ, b1, nullptr, nullptr, comb, g * G, 0);
    // out[b,o] (+)= Hp @ W2[group rows]  (+ gate-weighted b2 on first group)
    gemm_nt<1><<<dim3(8, 64), dim3(256), 0, stream>>>(
        Hp, G * H_SZ,
        W2T + (size_t)g * G * H_SZ, R_SZ * H_SZ, G * H_SZ,
        nullptr, 0, nullptr, out, b2, comb, 0, (g > 0) ? 1 : 0);
  }
}